// Round 10
// baseline (46.623 us; speedup 1.0000x reference)
//
#include <hip/hip_runtime.h>

constexpr int B = 16, N = 100000, C = 10, M = 32;
constexpr int THREADS = 256;
constexpr int BPB = 131;                     // 3 anchors/thread: 131*256*3 = 100608 >= N
                                             // 2096 blocks = 8.19/CU: ~single residency round
constexpr float F_EPS = 1e-4f;
constexpr float K_BG  = -0.75f * 0.69314718055994531f;  // -(1-alpha)*ln2
constexpr float K_TGT = -0.25f * 0.69314718055994531f;  // -alpha*ln2

struct PV { float v[C]; };

// section fence: stop IR load-hoisting (memory clobber) and scheduler remerge
__device__ __forceinline__ void section_fence() {
    asm volatile("" ::: "memory");
    __builtin_amdgcn_sched_barrier(0);
}

// ws layout: partials[B][BPB][3] floats = (cls_sum, reg_sum, pos_cnt)

__global__ __launch_bounds__(THREADS, 8) void focal_main(
    const float* __restrict__ cls,    // [B][N][C]
    const float* __restrict__ reg,    // [B][N][4]
    const float* __restrict__ anc,    // [B][N][4]
    const float* __restrict__ ann,    // [B][M][5]
    float* __restrict__ partials)
{
    const int b   = blockIdx.x / BPB;
    const int blk = blockIdx.x % BPB;

    __shared__ float4 s_box[M];
    __shared__ float  s_area[M];
    __shared__ float  s_lab[M];

    // parallel compaction of valid GT boxes (lanes 0..31 of wave 0);
    // zero-pad (pad boxes: inter=0, den=area_a>=256 -> iou=0, lose ties, never pos)
    if (threadIdx.x < M) {
        const int m = threadIdx.x;
        const float* a = ann + ((size_t)b * M + m) * 5;
        const float x0 = a[0], y0 = a[1], x1 = a[2], y1 = a[3], lb = a[4];
        const bool valid = (lb != -1.0f);
        const unsigned long long mask = __ballot(valid);
        const int nvalid = __popcll(mask);
        if (m >= nvalid) {
            s_box[m]  = make_float4(0.f, 0.f, 0.f, 0.f);
            s_area[m] = 0.f;
            s_lab[m]  = 0.f;
        }
        if (valid) {
            const int pos = __popcll(mask & ((1ull << m) - 1ull));
            s_box[pos]  = make_float4(x0, y0, x1, y1);
            s_area[pos] = (x1 - x0) * (y1 - y0);
            s_lab[pos]  = lb;
        }
    }
    __syncthreads();

    const size_t baseN = (size_t)b * N;
    const int n0 = blk * (3 * THREADS) + threadIdx.x;
    const int n1 = n0 + THREADS;
    const int n2 = n0 + 2 * THREADS;
    const bool v0 = n0 < N, v1 = n1 < N, v2 = n2 < N;
    // clamped indices: loads always legal; validity gates the math instead
    const int i0 = v0 ? n0 : N - 1;
    const int i1 = v1 ? n1 : N - 1;
    const int i2 = v2 ? n2 : N - 1;

    const float4 a0 = *reinterpret_cast<const float4*>(anc + (baseN + i0) * 4);
    const float4 a1 = *reinterpret_cast<const float4*>(anc + (baseN + i1) * 4);
    const float4 a2 = *reinterpret_cast<const float4*>(anc + (baseN + i2) * 4);
    const float ar0 = (a0.z - a0.x) * (a0.w - a0.y);
    const float ar1 = (a1.z - a1.x) * (a1.w - a1.y);
    const float ar2 = (a2.z - a2.x) * (a2.w - a2.y);

    auto loadPV = [&](int n) -> PV {
        PV r;
        const float2* cp2 = reinterpret_cast<const float2*>(cls + (baseN + n) * C);
        #pragma unroll
        for (int j = 0; j < C / 2; ++j) {
            const float2 v2f = cp2[j];
            r.v[2 * j]     = v2f.x;
            r.v[2 * j + 1] = v2f.y;
        }
        return r;
    };

    // pv0 issued before the IoU loop: latency hides under 96 IoU iterations
    PV pv0 = loadPV(i0);

    // packed (iou, 31-m) keys; umax => max-iou with first-index tie-break.
    // no den clamp: den = area_a + area_b - inter >= max(area) >= 256 > 0 always.
    unsigned best0 = 0u, best1 = 0u, best2 = 0u;
    #pragma unroll 8
    for (int m = 0; m < M; ++m) {
        const float4 bx = s_box[m];
        const float  sb = s_area[m];
        const unsigned tag = (unsigned)(31 - m);
        {
            const float iw = fminf(a0.z, bx.z) - fmaxf(a0.x, bx.x);
            const float ih = fminf(a0.w, bx.w) - fmaxf(a0.y, bx.y);
            const float inter = fmaxf(iw, 0.f) * fmaxf(ih, 0.f);
            const float iou = inter * __builtin_amdgcn_rcpf(ar0 + sb - inter);
            const unsigned key = (__float_as_uint(iou) & 0xFFFFFFE0u) | tag;
            best0 = key > best0 ? key : best0;
        }
        {
            const float iw = fminf(a1.z, bx.z) - fmaxf(a1.x, bx.x);
            const float ih = fminf(a1.w, bx.w) - fmaxf(a1.y, bx.y);
            const float inter = fmaxf(iw, 0.f) * fmaxf(ih, 0.f);
            const float iou = inter * __builtin_amdgcn_rcpf(ar1 + sb - inter);
            const unsigned key = (__float_as_uint(iou) & 0xFFFFFFE0u) | tag;
            best1 = key > best1 ? key : best1;
        }
        {
            const float iw = fminf(a2.z, bx.z) - fmaxf(a2.x, bx.x);
            const float ih = fminf(a2.w, bx.w) - fmaxf(a2.y, bx.y);
            const float inter = fmaxf(iw, 0.f) * fmaxf(ih, 0.f);
            const float iou = inter * __builtin_amdgcn_rcpf(ar2 + sb - inter);
            const unsigned key = (__float_as_uint(iou) & 0xFFFFFFE0u) | tag;
            best2 = key > best2 ? key : best2;
        }
    }

    float cls_sum = 0.f, reg_sum = 0.f, pos_cnt = 0.f;

    auto process = [&](bool v, float4 a4, unsigned best, int n, PV pv) {
        if (!v) return;
        const float iou_max = __uint_as_float(best & 0xFFFFFFE0u);
        const bool pos = iou_max >= 0.5f;
        const bool bg  = iou_max <  0.4f;
        if (!(pos || bg)) return;

        float S0 = 0.f, S1 = 0.f;
        #pragma unroll
        for (int j = 0; j < C; ++j) {
            const float p = __builtin_amdgcn_fmed3f(pv.v[j], F_EPS, 1.f - F_EPS);
            if (j & 1) S1 = fmaf(p * p, __log2f(1.f - p), S1);
            else       S0 = fmaf(p * p, __log2f(1.f - p), S0);
        }
        float contrib = K_BG * (S0 + S1);

        if (pos) {
            pos_cnt += 1.f;
            const int barg = 31 - (int)(best & 31u);
            const int tcls = (int)s_lab[barg];
            // select raw then clamp once: fmed3(select) == select(fmed3) element-wise
            float ptr_ = pv.v[0];
            #pragma unroll
            for (int j = 1; j < C; ++j) ptr_ = (j == tcls) ? pv.v[j] : ptr_;
            const float pt = __builtin_amdgcn_fmed3f(ptr_, F_EPS, 1.f - F_EPS);
            const float qt = 1.f - pt;
            contrib += K_TGT * qt * qt * __log2f(pt) - K_BG * pt * pt * __log2f(qt);

            const float4 g = s_box[barg];
            float gw = g.z - g.x, gh = g.w - g.y;
            const float gcx = g.x + 0.5f * gw, gcy = g.y + 0.5f * gh;
            const float aw = a4.z - a4.x, ah = a4.w - a4.y;
            const float acx = a4.x + 0.5f * aw, acy = a4.y + 0.5f * ah;
            gw = fmaxf(gw, 1.f);
            gh = fmaxf(gh, 1.f);
            const float raw = __builtin_amdgcn_rcpf(aw);
            const float rah = __builtin_amdgcn_rcpf(ah);
            const float t0 = (gcx - acx) * raw * 10.f;
            const float t1 = (gcy - acy) * rah * 10.f;
            const float t2 = __logf(gw * raw) * 5.f;
            const float t3 = __logf(gh * rah) * 5.f;
            const float4 r4 = *reinterpret_cast<const float4*>(reg + (baseN + n) * 4);
            const float d0 = fabsf(t0 - r4.x), d1 = fabsf(t1 - r4.y);
            const float d2 = fabsf(t2 - r4.z), d3 = fabsf(t3 - r4.w);
            const float TH = 1.f / 9.f, CC = 0.5f / 9.f;
            reg_sum += (d0 < TH ? 4.5f * d0 * d0 : d0 - CC)
                     + (d1 < TH ? 4.5f * d1 * d1 : d1 - CC)
                     + (d2 < TH ? 4.5f * d2 * d2 : d2 - CC)
                     + (d3 < TH ? 4.5f * d3 * d3 : d3 - CC);
        }
        cls_sum += contrib;
    };

    section_fence();
    process(v0, a0, best0, n0, pv0);

    section_fence();
    {
        PV pv1 = loadPV(i1);
        process(v1, a1, best1, n1, pv1);
    }

    section_fence();
    {
        PV pv2 = loadPV(i2);
        process(v2, a2, best2, n2, pv2);
    }
    section_fence();

    // 64-lane wave reduce, then cross-wave via LDS
    for (int off = 32; off > 0; off >>= 1) {
        cls_sum += __shfl_down(cls_sum, off);
        reg_sum += __shfl_down(reg_sum, off);
        pos_cnt += __shfl_down(pos_cnt, off);
    }
    __shared__ float s_red[3][THREADS / 64];
    const int wave = threadIdx.x >> 6;
    const int lane = threadIdx.x & 63;
    if (lane == 0) {
        s_red[0][wave] = cls_sum;
        s_red[1][wave] = reg_sum;
        s_red[2][wave] = pos_cnt;
    }
    __syncthreads();
    if (threadIdx.x == 0) {
        float cv = 0.f, rv = 0.f, pc = 0.f;
        #pragma unroll
        for (int w = 0; w < THREADS / 64; ++w) {
            cv += s_red[0][w]; rv += s_red[1][w]; pc += s_red[2][w];
        }
        float* outp = partials + ((size_t)b * BPB + blk) * 3;
        outp[0] = cv; outp[1] = rv; outp[2] = pc;
    }
}

__global__ __launch_bounds__(256) void focal_final(
    const float* __restrict__ partials,
    const float* __restrict__ ann,
    float* __restrict__ out)
{
    const int t = threadIdx.x;
    const int b = t >> 4, j = t & 15;
    float c = 0.f, r = 0.f, p = 0.f;
    for (int k = j; k < BPB; k += 16) {
        const float* pp = partials + ((size_t)b * BPB + k) * 3;
        c += pp[0]; r += pp[1]; p += pp[2];
    }
    for (int off = 8; off > 0; off >>= 1) {
        c += __shfl_down(c, off, 16);
        r += __shfl_down(r, off, 16);
        p += __shfl_down(p, off, 16);
    }
    __shared__ float s_c[B], s_r[B], s_h[B];
    if (j == 0) {
        float has = 0.f;
        for (int m = 0; m < M; ++m)
            if (ann[((size_t)b * M + m) * 5 + 4] != -1.f) has = 1.f;
        const float npf = fmaxf(p, 1.f);
        float cl = 0.f, rl = 0.f;
        if (p > 0.f) {
            cl = c / npf;
            rl = r / fmaxf(npf * 4.f, 1.f);
        }
        s_c[b] = cl * has;
        s_r[b] = rl * has;
        s_h[b] = has;
    }
    __syncthreads();
    if (t == 0) {
        float sc = 0.f, sr = 0.f, sh = 0.f;
        #pragma unroll
        for (int bb = 0; bb < B; ++bb) { sc += s_c[bb]; sr += s_r[bb]; sh += s_h[bb]; }
        const float denom = fmaxf(sh, 1.f);
        out[0] = sc / denom;
        out[1] = sr / denom;
    }
}

extern "C" void kernel_launch(void* const* d_in, const int* in_sizes, int n_in,
                              void* d_out, int out_size, void* d_ws, size_t ws_size,
                              hipStream_t stream) {
    const float* cls = (const float*)d_in[0];   // [16][100000][10]
    const float* reg = (const float*)d_in[1];   // [16][100000][4]
    const float* anc = (const float*)d_in[2];   // [16][100000][4]
    const float* ann = (const float*)d_in[3];   // [16][32][5]
    float* out = (float*)d_out;                 // 2 fp32 scalars
    float* partials = (float*)d_ws;             // 16*131*3 floats ~ 25 KB

    focal_main<<<B * BPB, THREADS, 0, stream>>>(cls, reg, anc, ann, partials);
    focal_final<<<1, 256, 0, stream>>>(partials, ann, out);
}

// Round 11
// 40.562 us; speedup vs baseline: 1.1494x; 1.1494x over previous
//
#include <hip/hip_runtime.h>

constexpr int B = 16, N = 100000, C = 10, M = 32;
constexpr int THREADS = 256;
constexpr int BPB = 131;                     // 3 anchors/thread: 131*256*3 = 100608 >= N
constexpr float F_EPS = 1e-4f;
constexpr float K_BG  = -0.75f * 0.69314718055994531f;  // -(1-alpha)*ln2
constexpr float K_TGT = -0.25f * 0.69314718055994531f;  // -alpha*ln2

struct PV { float v[C]; };

// ws layout: partials[B][BPB][3] floats = (cls_sum, reg_sum, pos_cnt)

// NOTE: min-waves=8 pins the allocator to a 32-VGPR budget on this toolchain
// (every (256,8) build reported exactly 32 VGPR; APT=3 then spills 40-50 MB).
// min-waves=4 doubles the budget; APT=3 peak liveness ~50 fits, and real
// occupancy is set by actual VGPR use (<=64 still allows 8 waves/SIMD).
__global__ __launch_bounds__(THREADS, 4) void focal_main(
    const float* __restrict__ cls,    // [B][N][C]
    const float* __restrict__ reg,    // [B][N][4]
    const float* __restrict__ anc,    // [B][N][4]
    const float* __restrict__ ann,    // [B][M][5]
    float* __restrict__ partials)
{
    const int b   = blockIdx.x / BPB;
    const int blk = blockIdx.x % BPB;

    __shared__ float4 s_box[M];
    __shared__ float  s_area[M];
    __shared__ float  s_lab[M];

    // parallel compaction of valid GT boxes (lanes 0..31 of wave 0);
    // zero-pad (pad boxes: inter=0, den=area_a>=256 -> iou=0, lose ties, never pos)
    if (threadIdx.x < M) {
        const int m = threadIdx.x;
        const float* a = ann + ((size_t)b * M + m) * 5;
        const float x0 = a[0], y0 = a[1], x1 = a[2], y1 = a[3], lb = a[4];
        const bool valid = (lb != -1.0f);
        const unsigned long long mask = __ballot(valid);
        const int nvalid = __popcll(mask);
        if (m >= nvalid) {
            s_box[m]  = make_float4(0.f, 0.f, 0.f, 0.f);
            s_area[m] = 0.f;
            s_lab[m]  = 0.f;
        }
        if (valid) {
            const int pos = __popcll(mask & ((1ull << m) - 1ull));
            s_box[pos]  = make_float4(x0, y0, x1, y1);
            s_area[pos] = (x1 - x0) * (y1 - y0);
            s_lab[pos]  = lb;
        }
    }
    __syncthreads();

    const size_t baseN = (size_t)b * N;
    const int n0 = blk * (3 * THREADS) + threadIdx.x;
    const int n1 = n0 + THREADS;
    const int n2 = n0 + 2 * THREADS;
    const bool v0 = n0 < N, v1 = n1 < N, v2 = n2 < N;
    // clamped indices: loads always legal; validity gates the math instead
    const int i0 = v0 ? n0 : N - 1;
    const int i1 = v1 ? n1 : N - 1;
    const int i2 = v2 ? n2 : N - 1;

    const float4 a0 = *reinterpret_cast<const float4*>(anc + (baseN + i0) * 4);
    const float4 a1 = *reinterpret_cast<const float4*>(anc + (baseN + i1) * 4);
    const float4 a2 = *reinterpret_cast<const float4*>(anc + (baseN + i2) * 4);
    const float ar0 = (a0.z - a0.x) * (a0.w - a0.y);
    const float ar1 = (a1.z - a1.x) * (a1.w - a1.y);
    const float ar2 = (a2.z - a2.x) * (a2.w - a2.y);

    auto loadPV = [&](int n) -> PV {
        PV r;
        const float2* cp2 = reinterpret_cast<const float2*>(cls + (baseN + n) * C);
        #pragma unroll
        for (int j = 0; j < C / 2; ++j) {
            const float2 v2f = cp2[j];
            r.v[2 * j]     = v2f.x;
            r.v[2 * j + 1] = v2f.y;
        }
        return r;
    };

    // pv0 issued before the IoU loop: latency hides under 96 IoU iterations
    PV pv0 = loadPV(i0);

    // packed (iou, 31-m) keys; umax => max-iou with first-index tie-break.
    // no den clamp: den = area_a + area_b - inter >= max(area) >= 256 > 0 always.
    unsigned best0 = 0u, best1 = 0u, best2 = 0u;
    #pragma unroll 8
    for (int m = 0; m < M; ++m) {
        const float4 bx = s_box[m];
        const float  sb = s_area[m];
        const unsigned tag = (unsigned)(31 - m);
        {
            const float iw = fminf(a0.z, bx.z) - fmaxf(a0.x, bx.x);
            const float ih = fminf(a0.w, bx.w) - fmaxf(a0.y, bx.y);
            const float inter = fmaxf(iw, 0.f) * fmaxf(ih, 0.f);
            const float iou = inter * __builtin_amdgcn_rcpf(ar0 + sb - inter);
            const unsigned key = (__float_as_uint(iou) & 0xFFFFFFE0u) | tag;
            best0 = key > best0 ? key : best0;
        }
        {
            const float iw = fminf(a1.z, bx.z) - fmaxf(a1.x, bx.x);
            const float ih = fminf(a1.w, bx.w) - fmaxf(a1.y, bx.y);
            const float inter = fmaxf(iw, 0.f) * fmaxf(ih, 0.f);
            const float iou = inter * __builtin_amdgcn_rcpf(ar1 + sb - inter);
            const unsigned key = (__float_as_uint(iou) & 0xFFFFFFE0u) | tag;
            best1 = key > best1 ? key : best1;
        }
        {
            const float iw = fminf(a2.z, bx.z) - fmaxf(a2.x, bx.x);
            const float ih = fminf(a2.w, bx.w) - fmaxf(a2.y, bx.y);
            const float inter = fmaxf(iw, 0.f) * fmaxf(ih, 0.f);
            const float iou = inter * __builtin_amdgcn_rcpf(ar2 + sb - inter);
            const unsigned key = (__float_as_uint(iou) & 0xFFFFFFE0u) | tag;
            best2 = key > best2 ? key : best2;
        }
    }

    float cls_sum = 0.f, reg_sum = 0.f, pos_cnt = 0.f;

    auto process = [&](bool v, float4 a4, unsigned best, int n, PV pv) {
        if (!v) return;
        const float iou_max = __uint_as_float(best & 0xFFFFFFE0u);
        const bool pos = iou_max >= 0.5f;
        const bool bg  = iou_max <  0.4f;
        if (!(pos || bg)) return;

        float S0 = 0.f, S1 = 0.f;
        #pragma unroll
        for (int j = 0; j < C; ++j) {
            const float p = __builtin_amdgcn_fmed3f(pv.v[j], F_EPS, 1.f - F_EPS);
            if (j & 1) S1 = fmaf(p * p, __log2f(1.f - p), S1);
            else       S0 = fmaf(p * p, __log2f(1.f - p), S0);
        }
        float contrib = K_BG * (S0 + S1);

        if (pos) {
            pos_cnt += 1.f;
            const int barg = 31 - (int)(best & 31u);
            const int tcls = (int)s_lab[barg];
            // select raw then clamp once: fmed3(select) == select(fmed3) element-wise
            float ptr_ = pv.v[0];
            #pragma unroll
            for (int j = 1; j < C; ++j) ptr_ = (j == tcls) ? pv.v[j] : ptr_;
            const float pt = __builtin_amdgcn_fmed3f(ptr_, F_EPS, 1.f - F_EPS);
            const float qt = 1.f - pt;
            contrib += K_TGT * qt * qt * __log2f(pt) - K_BG * pt * pt * __log2f(qt);

            const float4 g = s_box[barg];
            float gw = g.z - g.x, gh = g.w - g.y;
            const float gcx = g.x + 0.5f * gw, gcy = g.y + 0.5f * gh;
            const float aw = a4.z - a4.x, ah = a4.w - a4.y;
            const float acx = a4.x + 0.5f * aw, acy = a4.y + 0.5f * ah;
            gw = fmaxf(gw, 1.f);
            gh = fmaxf(gh, 1.f);
            const float raw = __builtin_amdgcn_rcpf(aw);
            const float rah = __builtin_amdgcn_rcpf(ah);
            const float t0 = (gcx - acx) * raw * 10.f;
            const float t1 = (gcy - acy) * rah * 10.f;
            const float t2 = __logf(gw * raw) * 5.f;
            const float t3 = __logf(gh * rah) * 5.f;
            const float4 r4 = *reinterpret_cast<const float4*>(reg + (baseN + n) * 4);
            const float d0 = fabsf(t0 - r4.x), d1 = fabsf(t1 - r4.y);
            const float d2 = fabsf(t2 - r4.z), d3 = fabsf(t3 - r4.w);
            const float TH = 1.f / 9.f, CC = 0.5f / 9.f;
            reg_sum += (d0 < TH ? 4.5f * d0 * d0 : d0 - CC)
                     + (d1 < TH ? 4.5f * d1 * d1 : d1 - CC)
                     + (d2 < TH ? 4.5f * d2 * d2 : d2 - CC)
                     + (d3 < TH ? 4.5f * d3 * d3 : d3 - CC);
        }
        cls_sum += contrib;
    };

    PV pv1 = loadPV(i1);                 // issue before process0; consumed after
    process(v0, a0, best0, n0, pv0);
    PV pv2 = loadPV(i2);                 // issue before process1; consumed after
    process(v1, a1, best1, n1, pv1);
    process(v2, a2, best2, n2, pv2);

    // 64-lane wave reduce, then cross-wave via LDS
    for (int off = 32; off > 0; off >>= 1) {
        cls_sum += __shfl_down(cls_sum, off);
        reg_sum += __shfl_down(reg_sum, off);
        pos_cnt += __shfl_down(pos_cnt, off);
    }
    __shared__ float s_red[3][THREADS / 64];
    const int wave = threadIdx.x >> 6;
    const int lane = threadIdx.x & 63;
    if (lane == 0) {
        s_red[0][wave] = cls_sum;
        s_red[1][wave] = reg_sum;
        s_red[2][wave] = pos_cnt;
    }
    __syncthreads();
    if (threadIdx.x == 0) {
        float cv = 0.f, rv = 0.f, pc = 0.f;
        #pragma unroll
        for (int w = 0; w < THREADS / 64; ++w) {
            cv += s_red[0][w]; rv += s_red[1][w]; pc += s_red[2][w];
        }
        float* outp = partials + ((size_t)b * BPB + blk) * 3;
        outp[0] = cv; outp[1] = rv; outp[2] = pc;
    }
}

__global__ __launch_bounds__(256) void focal_final(
    const float* __restrict__ partials,
    const float* __restrict__ ann,
    float* __restrict__ out)
{
    const int t = threadIdx.x;
    const int b = t >> 4, j = t & 15;
    float c = 0.f, r = 0.f, p = 0.f;
    for (int k = j; k < BPB; k += 16) {
        const float* pp = partials + ((size_t)b * BPB + k) * 3;
        c += pp[0]; r += pp[1]; p += pp[2];
    }
    for (int off = 8; off > 0; off >>= 1) {
        c += __shfl_down(c, off, 16);
        r += __shfl_down(r, off, 16);
        p += __shfl_down(p, off, 16);
    }
    __shared__ float s_c[B], s_r[B], s_h[B];
    if (j == 0) {
        float has = 0.f;
        for (int m = 0; m < M; ++m)
            if (ann[((size_t)b * M + m) * 5 + 4] != -1.f) has = 1.f;
        const float npf = fmaxf(p, 1.f);
        float cl = 0.f, rl = 0.f;
        if (p > 0.f) {
            cl = c / npf;
            rl = r / fmaxf(npf * 4.f, 1.f);
        }
        s_c[b] = cl * has;
        s_r[b] = rl * has;
        s_h[b] = has;
    }
    __syncthreads();
    if (t == 0) {
        float sc = 0.f, sr = 0.f, sh = 0.f;
        #pragma unroll
        for (int bb = 0; bb < B; ++bb) { sc += s_c[bb]; sr += s_r[bb]; sh += s_h[bb]; }
        const float denom = fmaxf(sh, 1.f);
        out[0] = sc / denom;
        out[1] = sr / denom;
    }
}

extern "C" void kernel_launch(void* const* d_in, const int* in_sizes, int n_in,
                              void* d_out, int out_size, void* d_ws, size_t ws_size,
                              hipStream_t stream) {
    const float* cls = (const float*)d_in[0];   // [16][100000][10]
    const float* reg = (const float*)d_in[1];   // [16][100000][4]
    const float* anc = (const float*)d_in[2];   // [16][100000][4]
    const float* ann = (const float*)d_in[3];   // [16][32][5]
    float* out = (float*)d_out;                 // 2 fp32 scalars
    float* partials = (float*)d_ws;             // 16*131*3 floats ~ 25 KB

    focal_main<<<B * BPB, THREADS, 0, stream>>>(cls, reg, anc, ann, partials);
    focal_final<<<1, 256, 0, stream>>>(partials, ann, out);
}